// Round 15
// baseline (137.454 us; speedup 1.0000x reference)
//
#include <hip/hip_runtime.h>

// Problem constants (B=2, W=2048, C=768, H=12, head dim 64)
constexpr int B_  = 2;
constexpr int W_  = 2048;
constexpr int C_  = 768;
constexpr int H_  = 12;
constexpr int HD  = 64;
constexpr int C3  = 3 * C_;           // 2304
constexpr int M_  = B_ * W_;          // 4096
constexpr int NSLOT = 80;             // (qtile,chunk) pairs per (b,h)

typedef float  f32x4 __attribute__((ext_vector_type(4)));
typedef short  s16x8 __attribute__((ext_vector_type(8)));
typedef short  s16x4 __attribute__((ext_vector_type(4)));
typedef unsigned short u16;
typedef unsigned int   u32;

// fp32 -> bf16 (round-to-nearest-even), bit pattern as ushort
__device__ __forceinline__ u16 f2bf(float f) {
    unsigned int u = __float_as_uint(f);
    u += 0x7FFFu + ((u >> 16) & 1u);
    return (u16)(u >> 16);
}
__device__ __forceinline__ float bf2f(u16 v) {
    return __uint_as_float(((u32)v) << 16);
}

// async global->LDS, 16 bytes per lane. LDS dest = wave-uniform base + lane*16.
__device__ __forceinline__ void gload_lds16(const u16* g, u16* l) {
    __builtin_amdgcn_global_load_lds(
        (const __attribute__((address_space(1))) unsigned int*)g,
        (__attribute__((address_space(3))) unsigned int*)l, 16, 0, 0);
}

// ---------------------------------------------------------------------------
// fp32 -> bf16 convert for WEIGHTS ONLY (w_attn, w_proj). x conversion is
// fused into GEMM1's A staging.
// ---------------------------------------------------------------------------
__global__ __launch_bounds__(256)
void cvt_w(const float* __restrict__ wa, const float* __restrict__ wp,
           u16* __restrict__ wab, u16* __restrict__ wpb)
{
    const int n0 = C3 * C_ / 8;
    const int n1 = n0 + C_ * C_ / 8;
    int i = blockIdx.x * 256 + threadIdx.x;
    const float* s; u16* d; int j;
    if (i < n0)      { s = wa; d = wab; j = i; }
    else if (i < n1) { s = wp; d = wpb; j = i - n0; }
    else return;
    const float4 a = reinterpret_cast<const float4*>(s)[j * 2];
    const float4 b = reinterpret_cast<const float4*>(s)[j * 2 + 1];
    s16x8 v;
    v[0] = (short)f2bf(a.x); v[1] = (short)f2bf(a.y);
    v[2] = (short)f2bf(a.z); v[3] = (short)f2bf(a.w);
    v[4] = (short)f2bf(b.x); v[5] = (short)f2bf(b.y);
    v[6] = (short)f2bf(b.z); v[7] = (short)f2bf(b.w);
    reinterpret_cast<s16x8*>(d)[j] = v;
}

// ---------------------------------------------------------------------------
// bf16 NT GEMM via MFMA, 128x128 tile, BK=64, 4 waves, fragment-major LDS.
// Templated A path:
//  - AT=float (GEMM1): A reg-staged from fp32 with in-register cvt_pk, written
//    to single-buffer As; B via gload_lds dbuf. Barrier-1 = __syncthreads
//    (vmcnt drain covered by previous compute); barrier-2 = raw s_barrier
//    with lgkmcnt(0) only (ds_writes visible; k+1 loads stay in flight).
//  - AT=u16 (GEMM2): both A and B via gload_lds dbuf, single barrier/iter
//    (round-14 schedule).
// ---------------------------------------------------------------------------
__device__ __forceinline__ void store_out(u16*  p, float v) { *p = f2bf(v); }
__device__ __forceinline__ void store_out(float* p, float v) { *p = v; }

template <typename AT, typename OutT>
__global__ __launch_bounds__(256)
void gemm_nt_mfma(const AT* __restrict__ A, const u16* __restrict__ Bm,
                  OutT* __restrict__ Y, int Ndim, int Kdim)
{
    constexpr bool A32 = (sizeof(AT) == 4);
    __shared__ __align__(16) u16 As[2][128 * 64];   // fp32 path uses As[0] only
    __shared__ __align__(16) u16 Bs[2][128 * 64];

    const int t  = threadIdx.x;
    const int w  = t >> 6;
    const int l  = t & 63;
    const int lg = l >> 4;
    const int ln = l & 15;
    const int wm = w >> 1;
    const int wn = w & 1;
    const int m0 = blockIdx.x * 128;
    const int n0 = blockIdx.y * 128;

    f32x4 acc[4][4];
    #pragma unroll
    for (int mi = 0; mi < 4; ++mi)
        #pragma unroll
        for (int ni = 0; ni < 4; ++ni)
            acc[mi][ni] = (f32x4){0.f, 0.f, 0.f, 0.f};

    // per-thread chunk source offsets (chunk c = t + it*256):
    // fr=c>>7, s=(c>>6)&1, kc=(c>>4)&3, rr=c&15 -> row fr*16+rr, k=s*32+kc*8
    size_t off[4];
    #pragma unroll
    for (int it = 0; it < 4; ++it) {
        const int c  = t + it * 256;
        off[it] = (size_t)((c >> 7) * 16 + (c & 15)) * Kdim
                + ((c >> 6) & 1) * 32 + ((c >> 4) & 3) * 8;
    }

    f32x4 ar[8];   // fp32-A staging regs (4 chunks x 8 floats)

    // ---- prologue: issue loads for k0 = 0 ----
    if constexpr (A32) {
        #pragma unroll
        for (int it = 0; it < 4; ++it) {
            const float* ga = A + (size_t)m0 * Kdim + off[it];
            ar[2 * it]     = *reinterpret_cast<const f32x4*>(ga);
            ar[2 * it + 1] = *reinterpret_cast<const f32x4*>(ga + 4);
        }
    } else {
        #pragma unroll
        for (int it = 0; it < 4; ++it)
            gload_lds16((const u16*)A + (size_t)m0 * Kdim + off[it],
                        &As[0][(size_t)(it * 256 + w * 64) * 8]);
    }
    #pragma unroll
    for (int it = 0; it < 4; ++it)
        gload_lds16(Bm + (size_t)n0 * Kdim + off[it],
                    &Bs[0][(size_t)(it * 256 + w * 64) * 8]);

    int cur = 0;
    for (int k0 = 0; k0 < Kdim; k0 += 64) {
        __syncthreads();   // k-tile loads done (drain covered by prev compute)

        if constexpr (A32) {
            // convert + write A(k) to LDS (fragment-major, conflict-free)
            #pragma unroll
            for (int it = 0; it < 4; ++it) {
                union { s16x8 v; u32 wd[4]; } pk;
                asm("v_cvt_pk_bf16_f32 %0, %1, %2"
                    : "=v"(pk.wd[0]) : "v"(ar[2*it][0]), "v"(ar[2*it][1]));
                asm("v_cvt_pk_bf16_f32 %0, %1, %2"
                    : "=v"(pk.wd[1]) : "v"(ar[2*it][2]), "v"(ar[2*it][3]));
                asm("v_cvt_pk_bf16_f32 %0, %1, %2"
                    : "=v"(pk.wd[2]) : "v"(ar[2*it+1][0]), "v"(ar[2*it+1][1]));
                asm("v_cvt_pk_bf16_f32 %0, %1, %2"
                    : "=v"(pk.wd[3]) : "v"(ar[2*it+1][2]), "v"(ar[2*it+1][3]));
                *reinterpret_cast<s16x8*>(&As[0][(size_t)(t + it * 256) * 8]) = pk.v;
            }
        }

        // issue next k-tile loads (fly across barrier-2 + compute)
        if (k0 + 64 < Kdim) {
            if constexpr (A32) {
                #pragma unroll
                for (int it = 0; it < 4; ++it) {
                    const float* ga = A + (size_t)m0 * Kdim + k0 + 64 + off[it];
                    ar[2 * it]     = *reinterpret_cast<const f32x4*>(ga);
                    ar[2 * it + 1] = *reinterpret_cast<const f32x4*>(ga + 4);
                }
            } else {
                #pragma unroll
                for (int it = 0; it < 4; ++it)
                    gload_lds16((const u16*)A + (size_t)m0 * Kdim + k0 + 64 + off[it],
                                &As[cur ^ 1][(size_t)(it * 256 + w * 64) * 8]);
            }
            #pragma unroll
            for (int it = 0; it < 4; ++it)
                gload_lds16(Bm + (size_t)n0 * Kdim + k0 + 64 + off[it],
                            &Bs[cur ^ 1][(size_t)(it * 256 + w * 64) * 8]);
        }

        if constexpr (A32) {
            // barrier-2: make As writes visible WITHOUT draining vmcnt
            asm volatile("s_waitcnt lgkmcnt(0)" ::: "memory");
            __builtin_amdgcn_sched_barrier(0);
            __builtin_amdgcn_s_barrier();
            __builtin_amdgcn_sched_barrier(0);
        }

        const u16* Asr = A32 ? As[0] : As[cur];
        #pragma unroll
        for (int s = 0; s < 2; ++s) {
            s16x8 af[4], bf[4];
            #pragma unroll
            for (int mi = 0; mi < 4; ++mi)
                af[mi] = *reinterpret_cast<const s16x8*>(
                    &Asr[(size_t)((wm * 4 + mi) * 128 + s * 64 + lg * 16 + ln) * 8]);
            #pragma unroll
            for (int ni = 0; ni < 4; ++ni)
                bf[ni] = *reinterpret_cast<const s16x8*>(
                    &Bs[cur][(size_t)((wn * 4 + ni) * 128 + s * 64 + lg * 16 + ln) * 8]);
            __builtin_amdgcn_s_setprio(1);
            #pragma unroll
            for (int mi = 0; mi < 4; ++mi)
                #pragma unroll
                for (int ni = 0; ni < 4; ++ni)
                    acc[mi][ni] = __builtin_amdgcn_mfma_f32_16x16x32_bf16(
                        af[mi], bf[ni], acc[mi][ni], 0, 0, 0);
            __builtin_amdgcn_s_setprio(0);
        }
        cur ^= 1;
    }

    #pragma unroll
    for (int mi = 0; mi < 4; ++mi) {
        const int row = m0 + wm * 64 + mi * 16 + lg * 4;
        #pragma unroll
        for (int ni = 0; ni < 4; ++ni) {
            const int col = n0 + wn * 64 + ni * 16 + ln;
            #pragma unroll
            for (int r = 0; r < 4; ++r)
                store_out(&Y[(size_t)(row + r) * Ndim + col], acc[mi][ni][r]);
        }
    }
}

// ---------------------------------------------------------------------------
// KV-split MFMA causal flash attention, partial pass (round-11 best body;
// only change: po partials now bf16 -> half the partial write traffic).
// ---------------------------------------------------------------------------
__global__ __launch_bounds__(256)
void attn_partial(const u16* __restrict__ qkv, u16* __restrict__ po,
                  float* __restrict__ pl)
{
    __shared__ __align__(16) unsigned char KsB[64 * 128];       // 8 KiB
    __shared__ __align__(16) unsigned char VtB[64 * 144];       // 9 KiB

    const int t  = threadIdx.x;
    const int w  = t >> 6;
    const int l  = t & 63;
    const int lg = l >> 4;
    const int ln = l & 15;
    const int p  = blockIdx.x;
    const int h  = blockIdx.y;
    const int b  = blockIdx.z;

    int qt, ck;
    if (p < 8)       { qt = p;                 ck = 0; }
    else if (p < 24) { qt = 8  + ((p - 8) >> 1);  ck = (p - 8) & 1; }
    else if (p < 48) { qt = 16 + (p - 24) / 3;    ck = (p - 24) % 3; }
    else             { qt = 24 + ((p - 48) >> 2); ck = (p - 48) & 3; }

    const int qb  = qt * 64;
    const int q0w = qb + w * 16;
    const int g0  = ck * 8;
    const int g1  = min(qt + 1, g0 + 8);
    const int slot = (b * H_ + h) * NSLOT + p;

    const u16* base  = qkv + (size_t)(b * W_) * C3;
    const u16* kbase = base + C_ + h * HD;
    const u16* vbase = base + 2 * C_ + h * HD;

    s16x8 qf[2];
    {
        const u16* qrow = base + (size_t)(q0w + ln) * C3 + h * HD;
        #pragma unroll
        for (int kc = 0; kc < 2; ++kc)
            qf[kc] = *reinterpret_cast<const s16x8*>(&qrow[kc * 32 + lg * 8]);
    }

    s16x8 onesf;
    {
        const short v1 = (ln == 0) ? (short)0x3F80 : (short)0;
        #pragma unroll
        for (int i = 0; i < 8; ++i) onesf[i] = v1;
    }

    f32x4 o[4];
    #pragma unroll
    for (int i = 0; i < 4; ++i) o[i] = (f32x4){0.f, 0.f, 0.f, 0.f};
    f32x4 o4 = (f32x4){0.f, 0.f, 0.f, 0.f};

    const float c1 = 0.18033688011112042f;   // (1/8) * log2(e)
    const float c2 = 17.312340490667562f;    // 12  * log2(e)

    const size_t sk_off = (size_t)((t >> 7) * 16 + (t & 15)) * C3
                        + ((t >> 6) & 1) * 32 + ((t >> 4) & 3) * 8;
    const bool vstage = (t < 128);
    const int vrun = (t >> 4) & 7;
    const int vK0  = (vrun >> 2) * 32 + (vrun & 3) * 4;
    const int vdq  = (t & 15) * 4;
    const int kfb  = l * 16;

    s16x8 kr[2];
    s16x4 vr[8];

    {
        const int s0 = g0 * 64;
        const u16* ks = kbase + (size_t)s0 * C3 + sk_off;
        kr[0] = *reinterpret_cast<const s16x8*>(ks);
        kr[1] = *reinterpret_cast<const s16x8*>(ks + (size_t)32 * C3);
        if (vstage) {
            const u16* vsrc = vbase + (size_t)(s0 + vK0) * C3 + vdq;
            #pragma unroll
            for (int e = 0; e < 8; ++e)
                vr[e] = *reinterpret_cast<const s16x4*>(
                    &vsrc[(size_t)((e >> 2) * 16 + (e & 3)) * C3]);
        }
    }

    for (int g = g0; g < g1; ++g) {
        const int s0 = g * 64;

        __syncthreads();

        *reinterpret_cast<s16x8*>(KsB + t * 16)         = kr[0];
        *reinterpret_cast<s16x8*>(KsB + (t + 256) * 16) = kr[1];
        if (vstage) {
            #pragma unroll
            for (int j = 0; j < 4; ++j) {
                s16x8 pk = { vr[0][j], vr[1][j], vr[2][j], vr[3][j],
                             vr[4][j], vr[5][j], vr[6][j], vr[7][j] };
                *reinterpret_cast<s16x8*>(
                    VtB + (vdq + j) * 144 + vrun * 16) = pk;
            }
        }

        if (g + 1 < g1) {
            const int s1 = s0 + 64;
            const u16* ks = kbase + (size_t)s1 * C3 + sk_off;
            kr[0] = *reinterpret_cast<const s16x8*>(ks);
            kr[1] = *reinterpret_cast<const s16x8*>(ks + (size_t)32 * C3);
            if (vstage) {
                const u16* vsrc = vbase + (size_t)(s1 + vK0) * C3 + vdq;
                #pragma unroll
                for (int e = 0; e < 8; ++e)
                    vr[e] = *reinterpret_cast<const s16x4*>(
                        &vsrc[(size_t)((e >> 2) * 16 + (e & 3)) * C3]);
            }
        }

        __syncthreads();

        #pragma unroll
        for (int c = 0; c < 2; ++c) {
            if (s0 + c * 32 <= q0w + 15) {
                float pt[2][4];
                #pragma unroll
                for (int n2 = 0; n2 < 2; ++n2) {
                    const unsigned char* kfrag = KsB + (c * 2 + n2) * 2048 + kfb;
                    s16x8 kf0 = *reinterpret_cast<const s16x8*>(kfrag);
                    s16x8 kf1 = *reinterpret_cast<const s16x8*>(kfrag + 1024);
                    f32x4 s = (f32x4){0.f, 0.f, 0.f, 0.f};
                    __builtin_amdgcn_s_setprio(1);
                    s = __builtin_amdgcn_mfma_f32_16x16x32_bf16(kf0, qf[0], s, 0, 0, 0);
                    s = __builtin_amdgcn_mfma_f32_16x16x32_bf16(kf1, qf[1], s, 0, 0, 0);
                    __builtin_amdgcn_s_setprio(0);
                    const int kg0   = s0 + c * 32 + n2 * 16 + lg * 4;
                    const int klast = s0 + c * 32 + n2 * 16 + 15;
                    if (klast <= q0w) {
                        #pragma unroll
                        for (int r = 0; r < 4; ++r)
                            pt[n2][r] = exp2f(fmaf(s[r], c1, -c2));
                    } else {
                        const int qg = q0w + ln;
                        #pragma unroll
                        for (int r = 0; r < 4; ++r)
                            pt[n2][r] = (kg0 + r <= qg)
                                      ? exp2f(fmaf(s[r], c1, -c2)) : 0.0f;
                    }
                }
                union { s16x8 v; u32 wd[4]; } afu;
                asm("v_cvt_pk_bf16_f32 %0, %1, %2"
                    : "=v"(afu.wd[0]) : "v"(pt[0][0]), "v"(pt[0][1]));
                asm("v_cvt_pk_bf16_f32 %0, %1, %2"
                    : "=v"(afu.wd[1]) : "v"(pt[0][2]), "v"(pt[0][3]));
                asm("v_cvt_pk_bf16_f32 %0, %1, %2"
                    : "=v"(afu.wd[2]) : "v"(pt[1][0]), "v"(pt[1][1]));
                asm("v_cvt_pk_bf16_f32 %0, %1, %2"
                    : "=v"(afu.wd[3]) : "v"(pt[1][2]), "v"(pt[1][3]));
                const s16x8 af = afu.v;
                s16x8 vf[4];
                #pragma unroll
                for (int dt = 0; dt < 4; ++dt)
                    vf[dt] = *reinterpret_cast<const s16x8*>(
                        VtB + (dt * 16 + ln) * 144 + c * 64 + lg * 16);
                __builtin_amdgcn_s_setprio(1);
                #pragma unroll
                for (int dt = 0; dt < 4; ++dt)
                    o[dt] = __builtin_amdgcn_mfma_f32_16x16x32_bf16(af, vf[dt], o[dt], 0, 0, 0);
                o4 = __builtin_amdgcn_mfma_f32_16x16x32_bf16(af, onesf, o4, 0, 0, 0);
                __builtin_amdgcn_s_setprio(0);
            }
        }
    }

    if (ln == 0) {
        #pragma unroll
        for (int r = 0; r < 4; ++r)
            pl[(size_t)slot * 64 + w * 16 + lg * 4 + r] = o4[r];
    }
    u16* os = po + (size_t)slot * 4096;
    #pragma unroll
    for (int r = 0; r < 4; ++r)
        #pragma unroll
        for (int dt = 0; dt < 4; ++dt)
            os[(w * 16 + lg * 4 + r) * 64 + dt * 16 + ln] = f2bf(o[dt][r]);
}

// ---------------------------------------------------------------------------
// Combine pass: sum <=4 bf16 chunk partials, normalize, emit bf16.
// ---------------------------------------------------------------------------
__global__ __launch_bounds__(256)
void attn_combine(const u16* __restrict__ po, const float* __restrict__ pl,
                  u16* __restrict__ aob)
{
    const int qt = blockIdx.x;
    const int h  = blockIdx.y;
    const int b  = blockIdx.z;
    const int nc = (qt + 8) >> 3;
    int cum;
    if (qt < 8)       cum = qt;
    else if (qt < 16) cum = 8  + 2 * (qt - 8);
    else if (qt < 24) cum = 24 + 3 * (qt - 16);
    else              cum = 48 + 4 * (qt - 24);
    const int slot0 = (b * H_ + h) * NSLOT + cum;

    const int tid = threadIdx.x;
    const int i   = tid >> 2;
    const int d0  = (tid & 3) * 16;

    float acc[16] = {};
    float lt = 0.0f;
    for (int c = 0; c < nc; ++c) {
        const u16* os = po + (size_t)(slot0 + c) * 4096 + i * 64 + d0;
        s16x8 v0 = *reinterpret_cast<const s16x8*>(os);
        s16x8 v1 = *reinterpret_cast<const s16x8*>(os + 8);
        #pragma unroll
        for (int e = 0; e < 8; ++e) {
            acc[e]     += bf2f((u16)v0[e]);
            acc[8 + e] += bf2f((u16)v1[e]);
        }
        lt += pl[(size_t)(slot0 + c) * 64 + i];
    }
    const float inv = 1.0f / lt;

    u16* dst = aob + (size_t)(b * W_ + qt * 64 + i) * C_ + h * HD + d0;
    s16x8 ov[2];
    #pragma unroll
    for (int e = 0; e < 8; ++e) {
        ov[0][e] = (short)f2bf(acc[e] * inv);
        ov[1][e] = (short)f2bf(acc[8 + e] * inv);
    }
    *reinterpret_cast<s16x8*>(dst)     = ov[0];
    *reinterpret_cast<s16x8*>(dst + 8) = ov[1];
}

// ---------------------------------------------------------------------------
extern "C" void kernel_launch(void* const* d_in, const int* in_sizes, int n_in,
                              void* d_out, int out_size, void* d_ws, size_t ws_size,
                              hipStream_t stream)
{
    const float* x      = (const float*)d_in[0];  // [B,W,C]
    const float* w_attn = (const float*)d_in[1];  // [3C,C]
    const float* w_proj = (const float*)d_in[2];  // [C,C]
    float* out = (float*)d_out;                   // [B,W,C]

    u16* wab  = (u16*)d_ws;                       // [3C, C]
    u16* wpb  = wab  + (size_t)C3 * C_;           // [C,  C]
    u16* qkvb = wpb  + (size_t)C_ * C_;           // [M, 3C]
    u16* aob  = qkvb + (size_t)M_ * C3;           // [M,  C]
    u16* po   = aob  + (size_t)M_ * C_;           // [1920][4096] bf16 15.7 MB
    float* pl = (float*)(po + (size_t)B_ * H_ * NSLOT * 4096);  // [1920][64]

    // 0) weight conversions only (x conversion fused into GEMM1)
    {
        const int total8 = (C3 * C_ + C_ * C_) / 8;
        cvt_w<<<(total8 + 255) / 256, 256, 0, stream>>>(w_attn, w_proj, wab, wpb);
    }

    // 1) QKV projection: qkvb = x(fp32) @ wab^T, A converted in staging
    {
        dim3 grid(M_ / 128, C3 / 128);
        gemm_nt_mfma<float, u16><<<grid, 256, 0, stream>>>(x, wab, qkvb, C3, C_);
    }

    // 2a) KV-split attention partials (1920 blocks, bf16 po)
    {
        dim3 grid(NSLOT, H_, B_);
        attn_partial<<<grid, 256, 0, stream>>>(qkvb, po, pl);
    }
    // 2b) combine + normalize
    {
        dim3 grid(W_ / 64, H_, B_);
        attn_combine<<<grid, 256, 0, stream>>>(po, pl, aob);
    }

    // 3) Output projection: out = aob @ wpb^T (bf16 gload path, fp32 out)
    {
        dim3 grid(M_ / 128, C_ / 128);
        gemm_nt_mfma<u16, float><<<grid, 256, 0, stream>>>(aob, wpb, out, C_, C_);
    }
}

// Round 16
// 118.273 us; speedup vs baseline: 1.1622x; 1.1622x over previous
//
#include <hip/hip_runtime.h>

// Problem constants (B=2, W=2048, C=768, H=12, head dim 64)
constexpr int B_  = 2;
constexpr int W_  = 2048;
constexpr int C_  = 768;
constexpr int H_  = 12;
constexpr int HD  = 64;
constexpr int C3  = 3 * C_;           // 2304
constexpr int M_  = B_ * W_;          // 4096
constexpr int NSLOT = 80;             // (qtile,chunk) pairs per (b,h)

typedef float  f32x4 __attribute__((ext_vector_type(4)));
typedef short  s16x8 __attribute__((ext_vector_type(8)));
typedef short  s16x4 __attribute__((ext_vector_type(4)));
typedef unsigned short u16;
typedef unsigned int   u32;

// fp32 -> bf16 (round-to-nearest-even), bit pattern as ushort
__device__ __forceinline__ u16 f2bf(float f) {
    unsigned int u = __float_as_uint(f);
    u += 0x7FFFu + ((u >> 16) & 1u);
    return (u16)(u >> 16);
}
__device__ __forceinline__ float bf2f(u16 v) {
    return __uint_as_float(((u32)v) << 16);
}

// async global->LDS, 16 bytes per lane. LDS dest = wave-uniform base + lane*16.
__device__ __forceinline__ void gload_lds16(const u16* g, u16* l) {
    __builtin_amdgcn_global_load_lds(
        (const __attribute__((address_space(1))) unsigned int*)g,
        (__attribute__((address_space(3))) unsigned int*)l, 16, 0, 0);
}

// ---------------------------------------------------------------------------
// fp32 -> bf16 bulk convert, all three tensors in one launch (8 elems/thread)
// ---------------------------------------------------------------------------
__global__ __launch_bounds__(256)
void cvt_all(const float* __restrict__ x, const float* __restrict__ wa,
             const float* __restrict__ wp, u16* __restrict__ xb,
             u16* __restrict__ wab, u16* __restrict__ wpb)
{
    const int n0 = M_ * C_ / 8;
    const int n1 = n0 + C3 * C_ / 8;
    const int n2 = n1 + C_ * C_ / 8;
    int i = blockIdx.x * 256 + threadIdx.x;
    const float* s; u16* d; int j;
    if (i < n0)      { s = x;  d = xb;  j = i; }
    else if (i < n1) { s = wa; d = wab; j = i - n0; }
    else if (i < n2) { s = wp; d = wpb; j = i - n1; }
    else return;
    const float4 a = reinterpret_cast<const float4*>(s)[j * 2];
    const float4 b = reinterpret_cast<const float4*>(s)[j * 2 + 1];
    s16x8 v;
    v[0] = (short)f2bf(a.x); v[1] = (short)f2bf(a.y);
    v[2] = (short)f2bf(a.z); v[3] = (short)f2bf(a.w);
    v[4] = (short)f2bf(b.x); v[5] = (short)f2bf(b.y);
    v[6] = (short)f2bf(b.z); v[7] = (short)f2bf(b.w);
    reinterpret_cast<s16x8*>(d)[j] = v;
}

// ---------------------------------------------------------------------------
// bf16 NT GEMM via MFMA, v4: 128x128 tile, BK=32, DOUBLE-BUFFERED, 32 KiB
// LDS total -> 5 blocks/CU capacity: GEMM1's 576 blocks are ALL resident in
// one dispatch round (no 2.25-round tail), and 4-5 co-resident blocks hide
// per-K-step latency (m114 mechanism). One __syncthreads per K-step; next
// tile's gload_lds issued before compute (drain covered by compute phase).
// No s_setprio (m190: hurts lockstep GEMM).
// Chunk c (0..511): fr=c>>6, kc=(c>>4)&3, rr=c&15 -> row fr*16+rr, k=kc*8.
// Fragment fr read = chunks [fr*64 .. fr*64+64) = contiguous 1 KiB.
// ---------------------------------------------------------------------------
__device__ __forceinline__ void store_out(u16*  p, float v) { *p = f2bf(v); }
__device__ __forceinline__ void store_out(float* p, float v) { *p = v; }

template <typename OutT>
__global__ __launch_bounds__(256)
void gemm_nt_mfma(const u16* __restrict__ A, const u16* __restrict__ Bm,
                  OutT* __restrict__ Y, int Ndim, int Kdim)
{
    __shared__ __align__(16) u16 As[2][128 * 32];   // 2 x 8 KiB
    __shared__ __align__(16) u16 Bs[2][128 * 32];   // 2 x 8 KiB

    const int t  = threadIdx.x;
    const int w  = t >> 6;
    const int l  = t & 63;
    const int lg = l >> 4;
    const int ln = l & 15;
    const int wm = w >> 1;
    const int wn = w & 1;
    const int m0 = blockIdx.x * 128;
    const int n0 = blockIdx.y * 128;

    f32x4 acc[4][4];
    #pragma unroll
    for (int mi = 0; mi < 4; ++mi)
        #pragma unroll
        for (int ni = 0; ni < 4; ++ni)
            acc[mi][ni] = (f32x4){0.f, 0.f, 0.f, 0.f};

    // per-thread chunk source offsets (chunks c = t, t+256)
    size_t off[2];
    #pragma unroll
    for (int it = 0; it < 2; ++it) {
        const int c  = t + it * 256;
        off[it] = (size_t)((c >> 6) * 16 + (c & 15)) * Kdim + ((c >> 4) & 3) * 8;
    }

    #define GEMM_STAGE(buf, k0s)                                              \
        _Pragma("unroll")                                                     \
        for (int it = 0; it < 2; ++it) {                                      \
            gload_lds16(A  + (size_t)m0 * Kdim + (k0s) + off[it],             \
                        &As[buf][(size_t)(it * 256 + w * 64) * 8]);           \
            gload_lds16(Bm + (size_t)n0 * Kdim + (k0s) + off[it],             \
                        &Bs[buf][(size_t)(it * 256 + w * 64) * 8]);           \
        }

    GEMM_STAGE(0, 0)
    __syncthreads();

    int cur = 0;
    for (int k0 = 0; k0 < Kdim; k0 += 32) {
        if (k0 + 32 < Kdim) { GEMM_STAGE(cur ^ 1, k0 + 32) }

        s16x8 af[4], bf[4];
        #pragma unroll
        for (int mi = 0; mi < 4; ++mi)
            af[mi] = *reinterpret_cast<const s16x8*>(
                &As[cur][(size_t)((wm * 4 + mi) * 64 + l) * 8]);
        #pragma unroll
        for (int ni = 0; ni < 4; ++ni)
            bf[ni] = *reinterpret_cast<const s16x8*>(
                &Bs[cur][(size_t)((wn * 4 + ni) * 64 + l) * 8]);
        #pragma unroll
        for (int mi = 0; mi < 4; ++mi)
            #pragma unroll
            for (int ni = 0; ni < 4; ++ni)
                acc[mi][ni] = __builtin_amdgcn_mfma_f32_16x16x32_bf16(
                    af[mi], bf[ni], acc[mi][ni], 0, 0, 0);

        __syncthreads();   // drain lands one compute phase after issue
        cur ^= 1;
    }
    #undef GEMM_STAGE

    #pragma unroll
    for (int mi = 0; mi < 4; ++mi) {
        const int row = m0 + wm * 64 + mi * 16 + lg * 4;
        #pragma unroll
        for (int ni = 0; ni < 4; ++ni) {
            const int col = n0 + wn * 64 + ni * 16 + ln;
            #pragma unroll
            for (int r = 0; r < 4; ++r)
                store_out(&Y[(size_t)(row + r) * Ndim + col], acc[mi][ni][r]);
        }
    }
}

// ---------------------------------------------------------------------------
// KV-split MFMA causal flash attention, partial pass (round-11 best body,
// bf16 po). New: biggest blocks dispatched FIRST (p = 79 - blockIdx.x) to
// kill the long-block tail behind short ones.
// ---------------------------------------------------------------------------
__global__ __launch_bounds__(256)
void attn_partial(const u16* __restrict__ qkv, u16* __restrict__ po,
                  float* __restrict__ pl)
{
    __shared__ __align__(16) unsigned char KsB[64 * 128];       // 8 KiB
    __shared__ __align__(16) unsigned char VtB[64 * 144];       // 9 KiB

    const int t  = threadIdx.x;
    const int w  = t >> 6;
    const int l  = t & 63;
    const int lg = l >> 4;
    const int ln = l & 15;
    const int p  = (NSLOT - 1) - (int)blockIdx.x;   // biggest-first
    const int h  = blockIdx.y;
    const int b  = blockIdx.z;

    int qt, ck;
    if (p < 8)       { qt = p;                 ck = 0; }
    else if (p < 24) { qt = 8  + ((p - 8) >> 1);  ck = (p - 8) & 1; }
    else if (p < 48) { qt = 16 + (p - 24) / 3;    ck = (p - 24) % 3; }
    else             { qt = 24 + ((p - 48) >> 2); ck = (p - 48) & 3; }

    const int qb  = qt * 64;
    const int q0w = qb + w * 16;
    const int g0  = ck * 8;
    const int g1  = min(qt + 1, g0 + 8);
    const int slot = (b * H_ + h) * NSLOT + p;

    const u16* base  = qkv + (size_t)(b * W_) * C3;
    const u16* kbase = base + C_ + h * HD;
    const u16* vbase = base + 2 * C_ + h * HD;

    s16x8 qf[2];
    {
        const u16* qrow = base + (size_t)(q0w + ln) * C3 + h * HD;
        #pragma unroll
        for (int kc = 0; kc < 2; ++kc)
            qf[kc] = *reinterpret_cast<const s16x8*>(&qrow[kc * 32 + lg * 8]);
    }

    s16x8 onesf;
    {
        const short v1 = (ln == 0) ? (short)0x3F80 : (short)0;
        #pragma unroll
        for (int i = 0; i < 8; ++i) onesf[i] = v1;
    }

    f32x4 o[4];
    #pragma unroll
    for (int i = 0; i < 4; ++i) o[i] = (f32x4){0.f, 0.f, 0.f, 0.f};
    f32x4 o4 = (f32x4){0.f, 0.f, 0.f, 0.f};

    const float c1 = 0.18033688011112042f;   // (1/8) * log2(e)
    const float c2 = 17.312340490667562f;    // 12  * log2(e)

    const size_t sk_off = (size_t)((t >> 7) * 16 + (t & 15)) * C3
                        + ((t >> 6) & 1) * 32 + ((t >> 4) & 3) * 8;
    const bool vstage = (t < 128);
    const int vrun = (t >> 4) & 7;
    const int vK0  = (vrun >> 2) * 32 + (vrun & 3) * 4;
    const int vdq  = (t & 15) * 4;
    const int kfb  = l * 16;

    s16x8 kr[2];
    s16x4 vr[8];

    {
        const int s0 = g0 * 64;
        const u16* ks = kbase + (size_t)s0 * C3 + sk_off;
        kr[0] = *reinterpret_cast<const s16x8*>(ks);
        kr[1] = *reinterpret_cast<const s16x8*>(ks + (size_t)32 * C3);
        if (vstage) {
            const u16* vsrc = vbase + (size_t)(s0 + vK0) * C3 + vdq;
            #pragma unroll
            for (int e = 0; e < 8; ++e)
                vr[e] = *reinterpret_cast<const s16x4*>(
                    &vsrc[(size_t)((e >> 2) * 16 + (e & 3)) * C3]);
        }
    }

    for (int g = g0; g < g1; ++g) {
        const int s0 = g * 64;

        __syncthreads();

        *reinterpret_cast<s16x8*>(KsB + t * 16)         = kr[0];
        *reinterpret_cast<s16x8*>(KsB + (t + 256) * 16) = kr[1];
        if (vstage) {
            #pragma unroll
            for (int j = 0; j < 4; ++j) {
                s16x8 pk = { vr[0][j], vr[1][j], vr[2][j], vr[3][j],
                             vr[4][j], vr[5][j], vr[6][j], vr[7][j] };
                *reinterpret_cast<s16x8*>(
                    VtB + (vdq + j) * 144 + vrun * 16) = pk;
            }
        }

        if (g + 1 < g1) {
            const int s1 = s0 + 64;
            const u16* ks = kbase + (size_t)s1 * C3 + sk_off;
            kr[0] = *reinterpret_cast<const s16x8*>(ks);
            kr[1] = *reinterpret_cast<const s16x8*>(ks + (size_t)32 * C3);
            if (vstage) {
                const u16* vsrc = vbase + (size_t)(s1 + vK0) * C3 + vdq;
                #pragma unroll
                for (int e = 0; e < 8; ++e)
                    vr[e] = *reinterpret_cast<const s16x4*>(
                        &vsrc[(size_t)((e >> 2) * 16 + (e & 3)) * C3]);
            }
        }

        __syncthreads();

        #pragma unroll
        for (int c = 0; c < 2; ++c) {
            if (s0 + c * 32 <= q0w + 15) {
                float pt[2][4];
                #pragma unroll
                for (int n2 = 0; n2 < 2; ++n2) {
                    const unsigned char* kfrag = KsB + (c * 2 + n2) * 2048 + kfb;
                    s16x8 kf0 = *reinterpret_cast<const s16x8*>(kfrag);
                    s16x8 kf1 = *reinterpret_cast<const s16x8*>(kfrag + 1024);
                    f32x4 s = (f32x4){0.f, 0.f, 0.f, 0.f};
                    __builtin_amdgcn_s_setprio(1);
                    s = __builtin_amdgcn_mfma_f32_16x16x32_bf16(kf0, qf[0], s, 0, 0, 0);
                    s = __builtin_amdgcn_mfma_f32_16x16x32_bf16(kf1, qf[1], s, 0, 0, 0);
                    __builtin_amdgcn_s_setprio(0);
                    const int kg0   = s0 + c * 32 + n2 * 16 + lg * 4;
                    const int klast = s0 + c * 32 + n2 * 16 + 15;
                    if (klast <= q0w) {
                        #pragma unroll
                        for (int r = 0; r < 4; ++r)
                            pt[n2][r] = exp2f(fmaf(s[r], c1, -c2));
                    } else {
                        const int qg = q0w + ln;
                        #pragma unroll
                        for (int r = 0; r < 4; ++r)
                            pt[n2][r] = (kg0 + r <= qg)
                                      ? exp2f(fmaf(s[r], c1, -c2)) : 0.0f;
                    }
                }
                union { s16x8 v; u32 wd[4]; } afu;
                asm("v_cvt_pk_bf16_f32 %0, %1, %2"
                    : "=v"(afu.wd[0]) : "v"(pt[0][0]), "v"(pt[0][1]));
                asm("v_cvt_pk_bf16_f32 %0, %1, %2"
                    : "=v"(afu.wd[1]) : "v"(pt[0][2]), "v"(pt[0][3]));
                asm("v_cvt_pk_bf16_f32 %0, %1, %2"
                    : "=v"(afu.wd[2]) : "v"(pt[1][0]), "v"(pt[1][1]));
                asm("v_cvt_pk_bf16_f32 %0, %1, %2"
                    : "=v"(afu.wd[3]) : "v"(pt[1][2]), "v"(pt[1][3]));
                const s16x8 af = afu.v;
                s16x8 vf[4];
                #pragma unroll
                for (int dt = 0; dt < 4; ++dt)
                    vf[dt] = *reinterpret_cast<const s16x8*>(
                        VtB + (dt * 16 + ln) * 144 + c * 64 + lg * 16);
                __builtin_amdgcn_s_setprio(1);
                #pragma unroll
                for (int dt = 0; dt < 4; ++dt)
                    o[dt] = __builtin_amdgcn_mfma_f32_16x16x32_bf16(af, vf[dt], o[dt], 0, 0, 0);
                o4 = __builtin_amdgcn_mfma_f32_16x16x32_bf16(af, onesf, o4, 0, 0, 0);
                __builtin_amdgcn_s_setprio(0);
            }
        }
    }

    if (ln == 0) {
        #pragma unroll
        for (int r = 0; r < 4; ++r)
            pl[(size_t)slot * 64 + w * 16 + lg * 4 + r] = o4[r];
    }
    u16* os = po + (size_t)slot * 4096;
    #pragma unroll
    for (int r = 0; r < 4; ++r)
        #pragma unroll
        for (int dt = 0; dt < 4; ++dt)
            os[(w * 16 + lg * 4 + r) * 64 + dt * 16 + ln] = f2bf(o[dt][r]);
}

// ---------------------------------------------------------------------------
// Combine pass: sum <=4 bf16 chunk partials, normalize, emit bf16.
// ---------------------------------------------------------------------------
__global__ __launch_bounds__(256)
void attn_combine(const u16* __restrict__ po, const float* __restrict__ pl,
                  u16* __restrict__ aob)
{
    const int qt = blockIdx.x;
    const int h  = blockIdx.y;
    const int b  = blockIdx.z;
    const int nc = (qt + 8) >> 3;
    int cum;
    if (qt < 8)       cum = qt;
    else if (qt < 16) cum = 8  + 2 * (qt - 8);
    else if (qt < 24) cum = 24 + 3 * (qt - 16);
    else              cum = 48 + 4 * (qt - 24);
    const int slot0 = (b * H_ + h) * NSLOT + cum;

    const int tid = threadIdx.x;
    const int i   = tid >> 2;
    const int d0  = (tid & 3) * 16;

    float acc[16] = {};
    float lt = 0.0f;
    for (int c = 0; c < nc; ++c) {
        const u16* os = po + (size_t)(slot0 + c) * 4096 + i * 64 + d0;
        s16x8 v0 = *reinterpret_cast<const s16x8*>(os);
        s16x8 v1 = *reinterpret_cast<const s16x8*>(os + 8);
        #pragma unroll
        for (int e = 0; e < 8; ++e) {
            acc[e]     += bf2f((u16)v0[e]);
            acc[8 + e] += bf2f((u16)v1[e]);
        }
        lt += pl[(size_t)(slot0 + c) * 64 + i];
    }
    const float inv = 1.0f / lt;

    u16* dst = aob + (size_t)(b * W_ + qt * 64 + i) * C_ + h * HD + d0;
    s16x8 ov[2];
    #pragma unroll
    for (int e = 0; e < 8; ++e) {
        ov[0][e] = (short)f2bf(acc[e] * inv);
        ov[1][e] = (short)f2bf(acc[8 + e] * inv);
    }
    *reinterpret_cast<s16x8*>(dst)     = ov[0];
    *reinterpret_cast<s16x8*>(dst + 8) = ov[1];
}

// ---------------------------------------------------------------------------
extern "C" void kernel_launch(void* const* d_in, const int* in_sizes, int n_in,
                              void* d_out, int out_size, void* d_ws, size_t ws_size,
                              hipStream_t stream)
{
    const float* x      = (const float*)d_in[0];  // [B,W,C]
    const float* w_attn = (const float*)d_in[1];  // [3C,C]
    const float* w_proj = (const float*)d_in[2];  // [C,C]
    float* out = (float*)d_out;                   // [B,W,C]

    u16* xb   = (u16*)d_ws;                       // [M,  C]
    u16* wab  = xb   + (size_t)M_ * C_;           // [3C, C]
    u16* wpb  = wab  + (size_t)C3 * C_;           // [C,  C]
    u16* qkvb = wpb  + (size_t)C_ * C_;           // [M, 3C]
    u16* aob  = qkvb + (size_t)M_ * C3;           // [M,  C]
    u16* po   = aob  + (size_t)M_ * C_;           // [1920][4096] bf16
    float* pl = (float*)(po + (size_t)B_ * H_ * NSLOT * 4096);  // [1920][64]

    // 0) fp32 -> bf16 conversions (single launch)
    {
        const int total8 = (M_ * C_ + C3 * C_ + C_ * C_) / 8;
        cvt_all<<<(total8 + 255) / 256, 256, 0, stream>>>(
            x, w_attn, w_proj, xb, wab, wpb);
    }

    // 1) QKV projection (bf16 MFMA, 128x128, BK=32 dbuf, 32 KiB LDS)
    {
        dim3 grid(M_ / 128, C3 / 128);   // 576 blocks, all resident (5/CU cap)
        gemm_nt_mfma<u16><<<grid, 256, 0, stream>>>(xb, wab, qkvb, C3, C_);
    }

    // 2a) KV-split attention partials (1920 blocks, biggest-first)
    {
        dim3 grid(NSLOT, H_, B_);
        attn_partial<<<grid, 256, 0, stream>>>(qkvb, po, pl);
    }
    // 2b) combine + normalize
    {
        dim3 grid(W_ / 64, H_, B_);
        attn_combine<<<grid, 256, 0, stream>>>(po, pl, aob);
    }

    // 3) Output projection: out = aob @ wpb^T (fp32 out)
    {
        dim3 grid(M_ / 128, C_ / 128);   // 192 blocks
        gemm_nt_mfma<float><<<grid, 256, 0, stream>>>(aob, wpb, out, C_, C_);
    }
}

// Round 17
// 117.907 us; speedup vs baseline: 1.1658x; 1.0031x over previous
//
#include <hip/hip_runtime.h>

// Problem constants (B=2, W=2048, C=768, H=12, head dim 64)
constexpr int B_  = 2;
constexpr int W_  = 2048;
constexpr int C_  = 768;
constexpr int H_  = 12;
constexpr int HD  = 64;
constexpr int C3  = 3 * C_;           // 2304
constexpr int M_  = B_ * W_;          // 4096
constexpr int NSLOT = 80;             // (qtile,chunk) pairs per (b,h)

typedef float  f32x4 __attribute__((ext_vector_type(4)));
typedef short  s16x8 __attribute__((ext_vector_type(8)));
typedef short  s16x4 __attribute__((ext_vector_type(4)));
typedef unsigned short u16;
typedef unsigned int   u32;

// fp32 -> bf16 (round-to-nearest-even), bit pattern as ushort
__device__ __forceinline__ u16 f2bf(float f) {
    unsigned int u = __float_as_uint(f);
    u += 0x7FFFu + ((u >> 16) & 1u);
    return (u16)(u >> 16);
}
__device__ __forceinline__ float bf2f(u16 v) {
    return __uint_as_float(((u32)v) << 16);
}

// async global->LDS, 16 bytes per lane. LDS dest = wave-uniform base + lane*16.
__device__ __forceinline__ void gload_lds16(const u16* g, u16* l) {
    __builtin_amdgcn_global_load_lds(
        (const __attribute__((address_space(1))) unsigned int*)g,
        (__attribute__((address_space(3))) unsigned int*)l, 16, 0, 0);
}

// ---------------------------------------------------------------------------
// fp32 -> bf16 bulk convert, all three tensors in one launch (8 elems/thread)
// ---------------------------------------------------------------------------
__global__ __launch_bounds__(256)
void cvt_all(const float* __restrict__ x, const float* __restrict__ wa,
             const float* __restrict__ wp, u16* __restrict__ xb,
             u16* __restrict__ wab, u16* __restrict__ wpb)
{
    const int n0 = M_ * C_ / 8;
    const int n1 = n0 + C3 * C_ / 8;
    const int n2 = n1 + C_ * C_ / 8;
    int i = blockIdx.x * 256 + threadIdx.x;
    const float* s; u16* d; int j;
    if (i < n0)      { s = x;  d = xb;  j = i; }
    else if (i < n1) { s = wa; d = wab; j = i - n0; }
    else if (i < n2) { s = wp; d = wpb; j = i - n1; }
    else return;
    const float4 a = reinterpret_cast<const float4*>(s)[j * 2];
    const float4 b = reinterpret_cast<const float4*>(s)[j * 2 + 1];
    s16x8 v;
    v[0] = (short)f2bf(a.x); v[1] = (short)f2bf(a.y);
    v[2] = (short)f2bf(a.z); v[3] = (short)f2bf(a.w);
    v[4] = (short)f2bf(b.x); v[5] = (short)f2bf(b.y);
    v[6] = (short)f2bf(b.z); v[7] = (short)f2bf(b.w);
    reinterpret_cast<s16x8*>(d)[j] = v;
}

// ---------------------------------------------------------------------------
// bf16 NT GEMM via MFMA, v5: 128x128 tile, BK=32, TRIPLE-BUFFERED with
// counted vmcnt (prefetch depth 2). Rationale: per-K-step compute (~200-400
// cy) < HBM/L2 latency (~500-900 cy), so 2-phase leaves a residual drain at
// every barrier; depth-2 gives each tile's loads TWO compute phases to land.
//   prologue: S(0)->b0, S(1)->b1            (8 gloads in flight)
//   iter g:   wait vmcnt(4) [last: 0]       <- S(g) done, S(g+1) in flight
//             s_barrier                     <- all waves' S(g) visible;
//                                              readers of buf[(g+2)%3] done
//             issue S(g+2) -> buf[(g+2)%3]
//             compute(buf[g%3])             (no trailing barrier)
// Race audit: S(g+2) writes a buffer last read by compute(g-1); every wave
// passed this iter's barrier only after finishing compute(g-1). compute(g)
// reads after own vmcnt wait + barrier (covers other waves' loads).
// LDS 48 KiB -> 3 blocks/CU >= grid demand (2.25/CU) -> all blocks resident.
// Chunk c (0..511): fr=c>>6, kc=(c>>4)&3, rr=c&15 -> row fr*16+rr, k=kc*8.
// Fragment fr read = chunks [fr*64 .. fr*64+64) = contiguous 1 KiB.
// ---------------------------------------------------------------------------
__device__ __forceinline__ void store_out(u16*  p, float v) { *p = f2bf(v); }
__device__ __forceinline__ void store_out(float* p, float v) { *p = v; }

template <typename OutT>
__global__ __launch_bounds__(256)
void gemm_nt_mfma(const u16* __restrict__ A, const u16* __restrict__ Bm,
                  OutT* __restrict__ Y, int Ndim, int Kdim)
{
    __shared__ __align__(16) u16 As[3][128 * 32];   // 3 x 8 KiB
    __shared__ __align__(16) u16 Bs[3][128 * 32];   // 3 x 8 KiB

    const int t  = threadIdx.x;
    const int w  = t >> 6;
    const int l  = t & 63;
    const int lg = l >> 4;
    const int ln = l & 15;
    const int wm = w >> 1;
    const int wn = w & 1;
    const int m0 = blockIdx.x * 128;
    const int n0 = blockIdx.y * 128;

    f32x4 acc[4][4];
    #pragma unroll
    for (int mi = 0; mi < 4; ++mi)
        #pragma unroll
        for (int ni = 0; ni < 4; ++ni)
            acc[mi][ni] = (f32x4){0.f, 0.f, 0.f, 0.f};

    // per-thread chunk source offsets (chunks c = t, t+256)
    size_t off[2];
    #pragma unroll
    for (int it = 0; it < 2; ++it) {
        const int c  = t + it * 256;
        off[it] = (size_t)((c >> 6) * 16 + (c & 15)) * Kdim + ((c >> 4) & 3) * 8;
    }

    #define GEMM_STAGE(buf, k0s)                                              \
        _Pragma("unroll")                                                     \
        for (int it = 0; it < 2; ++it) {                                      \
            gload_lds16(A  + (size_t)m0 * Kdim + (k0s) + off[it],             \
                        &As[buf][(size_t)(it * 256 + w * 64) * 8]);           \
            gload_lds16(Bm + (size_t)n0 * Kdim + (k0s) + off[it],             \
                        &Bs[buf][(size_t)(it * 256 + w * 64) * 8]);           \
        }

    // prologue: two tiles in flight
    GEMM_STAGE(0, 0)
    GEMM_STAGE(1, 32)

    int cur = 0;
    for (int k0 = 0; k0 < Kdim; k0 += 32) {
        // wait for tile g's 4 gloads (leave S(g+1)'s 4 in flight)
        if (k0 + 32 < Kdim)
            asm volatile("s_waitcnt vmcnt(4)" ::: "memory");
        else
            asm volatile("s_waitcnt vmcnt(0)" ::: "memory");
        __builtin_amdgcn_s_barrier();

        // issue tile g+2 (its buffer's readers finished before this barrier)
        const int nx2 = (cur + 2 >= 3) ? cur - 1 : cur + 2;
        if (k0 + 64 < Kdim) { GEMM_STAGE(nx2, k0 + 64) }

        s16x8 af[4], bf[4];
        #pragma unroll
        for (int mi = 0; mi < 4; ++mi)
            af[mi] = *reinterpret_cast<const s16x8*>(
                &As[cur][(size_t)((wm * 4 + mi) * 64 + l) * 8]);
        #pragma unroll
        for (int ni = 0; ni < 4; ++ni)
            bf[ni] = *reinterpret_cast<const s16x8*>(
                &Bs[cur][(size_t)((wn * 4 + ni) * 64 + l) * 8]);
        #pragma unroll
        for (int mi = 0; mi < 4; ++mi)
            #pragma unroll
            for (int ni = 0; ni < 4; ++ni)
                acc[mi][ni] = __builtin_amdgcn_mfma_f32_16x16x32_bf16(
                    af[mi], bf[ni], acc[mi][ni], 0, 0, 0);

        cur = (cur == 2) ? 0 : cur + 1;
    }
    #undef GEMM_STAGE

    #pragma unroll
    for (int mi = 0; mi < 4; ++mi) {
        const int row = m0 + wm * 64 + mi * 16 + lg * 4;
        #pragma unroll
        for (int ni = 0; ni < 4; ++ni) {
            const int col = n0 + wn * 64 + ni * 16 + ln;
            #pragma unroll
            for (int r = 0; r < 4; ++r)
                store_out(&Y[(size_t)(row + r) * Ndim + col], acc[mi][ni][r]);
        }
    }
}

// ---------------------------------------------------------------------------
// KV-split MFMA causal flash attention, partial pass (round-16 kernel,
// verbatim — best measured 48.0 us). Fragment-major K, conflict-free V^T
// staging, swapped QK^T, lane-local P, cvt_pk pack, mask-free fast path,
// ones-MFMA row-sum, bf16 po, biggest-first dispatch.
// ---------------------------------------------------------------------------
__global__ __launch_bounds__(256)
void attn_partial(const u16* __restrict__ qkv, u16* __restrict__ po,
                  float* __restrict__ pl)
{
    __shared__ __align__(16) unsigned char KsB[64 * 128];       // 8 KiB
    __shared__ __align__(16) unsigned char VtB[64 * 144];       // 9 KiB

    const int t  = threadIdx.x;
    const int w  = t >> 6;
    const int l  = t & 63;
    const int lg = l >> 4;
    const int ln = l & 15;
    const int p  = (NSLOT - 1) - (int)blockIdx.x;   // biggest-first
    const int h  = blockIdx.y;
    const int b  = blockIdx.z;

    int qt, ck;
    if (p < 8)       { qt = p;                 ck = 0; }
    else if (p < 24) { qt = 8  + ((p - 8) >> 1);  ck = (p - 8) & 1; }
    else if (p < 48) { qt = 16 + (p - 24) / 3;    ck = (p - 24) % 3; }
    else             { qt = 24 + ((p - 48) >> 2); ck = (p - 48) & 3; }

    const int qb  = qt * 64;
    const int q0w = qb + w * 16;
    const int g0  = ck * 8;
    const int g1  = min(qt + 1, g0 + 8);
    const int slot = (b * H_ + h) * NSLOT + p;

    const u16* base  = qkv + (size_t)(b * W_) * C3;
    const u16* kbase = base + C_ + h * HD;
    const u16* vbase = base + 2 * C_ + h * HD;

    s16x8 qf[2];
    {
        const u16* qrow = base + (size_t)(q0w + ln) * C3 + h * HD;
        #pragma unroll
        for (int kc = 0; kc < 2; ++kc)
            qf[kc] = *reinterpret_cast<const s16x8*>(&qrow[kc * 32 + lg * 8]);
    }

    s16x8 onesf;
    {
        const short v1 = (ln == 0) ? (short)0x3F80 : (short)0;
        #pragma unroll
        for (int i = 0; i < 8; ++i) onesf[i] = v1;
    }

    f32x4 o[4];
    #pragma unroll
    for (int i = 0; i < 4; ++i) o[i] = (f32x4){0.f, 0.f, 0.f, 0.f};
    f32x4 o4 = (f32x4){0.f, 0.f, 0.f, 0.f};

    const float c1 = 0.18033688011112042f;   // (1/8) * log2(e)
    const float c2 = 17.312340490667562f;    // 12  * log2(e)

    const size_t sk_off = (size_t)((t >> 7) * 16 + (t & 15)) * C3
                        + ((t >> 6) & 1) * 32 + ((t >> 4) & 3) * 8;
    const bool vstage = (t < 128);
    const int vrun = (t >> 4) & 7;
    const int vK0  = (vrun >> 2) * 32 + (vrun & 3) * 4;
    const int vdq  = (t & 15) * 4;
    const int kfb  = l * 16;

    s16x8 kr[2];
    s16x4 vr[8];

    {
        const int s0 = g0 * 64;
        const u16* ks = kbase + (size_t)s0 * C3 + sk_off;
        kr[0] = *reinterpret_cast<const s16x8*>(ks);
        kr[1] = *reinterpret_cast<const s16x8*>(ks + (size_t)32 * C3);
        if (vstage) {
            const u16* vsrc = vbase + (size_t)(s0 + vK0) * C3 + vdq;
            #pragma unroll
            for (int e = 0; e < 8; ++e)
                vr[e] = *reinterpret_cast<const s16x4*>(
                    &vsrc[(size_t)((e >> 2) * 16 + (e & 3)) * C3]);
        }
    }

    for (int g = g0; g < g1; ++g) {
        const int s0 = g * 64;

        __syncthreads();

        *reinterpret_cast<s16x8*>(KsB + t * 16)         = kr[0];
        *reinterpret_cast<s16x8*>(KsB + (t + 256) * 16) = kr[1];
        if (vstage) {
            #pragma unroll
            for (int j = 0; j < 4; ++j) {
                s16x8 pk = { vr[0][j], vr[1][j], vr[2][j], vr[3][j],
                             vr[4][j], vr[5][j], vr[6][j], vr[7][j] };
                *reinterpret_cast<s16x8*>(
                    VtB + (vdq + j) * 144 + vrun * 16) = pk;
            }
        }

        if (g + 1 < g1) {
            const int s1 = s0 + 64;
            const u16* ks = kbase + (size_t)s1 * C3 + sk_off;
            kr[0] = *reinterpret_cast<const s16x8*>(ks);
            kr[1] = *reinterpret_cast<const s16x8*>(ks + (size_t)32 * C3);
            if (vstage) {
                const u16* vsrc = vbase + (size_t)(s1 + vK0) * C3 + vdq;
                #pragma unroll
                for (int e = 0; e < 8; ++e)
                    vr[e] = *reinterpret_cast<const s16x4*>(
                        &vsrc[(size_t)((e >> 2) * 16 + (e & 3)) * C3]);
            }
        }

        __syncthreads();

        #pragma unroll
        for (int c = 0; c < 2; ++c) {
            if (s0 + c * 32 <= q0w + 15) {
                float pt[2][4];
                #pragma unroll
                for (int n2 = 0; n2 < 2; ++n2) {
                    const unsigned char* kfrag = KsB + (c * 2 + n2) * 2048 + kfb;
                    s16x8 kf0 = *reinterpret_cast<const s16x8*>(kfrag);
                    s16x8 kf1 = *reinterpret_cast<const s16x8*>(kfrag + 1024);
                    f32x4 s = (f32x4){0.f, 0.f, 0.f, 0.f};
                    __builtin_amdgcn_s_setprio(1);
                    s = __builtin_amdgcn_mfma_f32_16x16x32_bf16(kf0, qf[0], s, 0, 0, 0);
                    s = __builtin_amdgcn_mfma_f32_16x16x32_bf16(kf1, qf[1], s, 0, 0, 0);
                    __builtin_amdgcn_s_setprio(0);
                    const int kg0   = s0 + c * 32 + n2 * 16 + lg * 4;
                    const int klast = s0 + c * 32 + n2 * 16 + 15;
                    if (klast <= q0w) {
                        #pragma unroll
                        for (int r = 0; r < 4; ++r)
                            pt[n2][r] = exp2f(fmaf(s[r], c1, -c2));
                    } else {
                        const int qg = q0w + ln;
                        #pragma unroll
                        for (int r = 0; r < 4; ++r)
                            pt[n2][r] = (kg0 + r <= qg)
                                      ? exp2f(fmaf(s[r], c1, -c2)) : 0.0f;
                    }
                }
                union { s16x8 v; u32 wd[4]; } afu;
                asm("v_cvt_pk_bf16_f32 %0, %1, %2"
                    : "=v"(afu.wd[0]) : "v"(pt[0][0]), "v"(pt[0][1]));
                asm("v_cvt_pk_bf16_f32 %0, %1, %2"
                    : "=v"(afu.wd[1]) : "v"(pt[0][2]), "v"(pt[0][3]));
                asm("v_cvt_pk_bf16_f32 %0, %1, %2"
                    : "=v"(afu.wd[2]) : "v"(pt[1][0]), "v"(pt[1][1]));
                asm("v_cvt_pk_bf16_f32 %0, %1, %2"
                    : "=v"(afu.wd[3]) : "v"(pt[1][2]), "v"(pt[1][3]));
                const s16x8 af = afu.v;
                s16x8 vf[4];
                #pragma unroll
                for (int dt = 0; dt < 4; ++dt)
                    vf[dt] = *reinterpret_cast<const s16x8*>(
                        VtB + (dt * 16 + ln) * 144 + c * 64 + lg * 16);
                __builtin_amdgcn_s_setprio(1);
                #pragma unroll
                for (int dt = 0; dt < 4; ++dt)
                    o[dt] = __builtin_amdgcn_mfma_f32_16x16x32_bf16(af, vf[dt], o[dt], 0, 0, 0);
                o4 = __builtin_amdgcn_mfma_f32_16x16x32_bf16(af, onesf, o4, 0, 0, 0);
                __builtin_amdgcn_s_setprio(0);
            }
        }
    }

    if (ln == 0) {
        #pragma unroll
        for (int r = 0; r < 4; ++r)
            pl[(size_t)slot * 64 + w * 16 + lg * 4 + r] = o4[r];
    }
    u16* os = po + (size_t)slot * 4096;
    #pragma unroll
    for (int r = 0; r < 4; ++r)
        #pragma unroll
        for (int dt = 0; dt < 4; ++dt)
            os[(w * 16 + lg * 4 + r) * 64 + dt * 16 + ln] = f2bf(o[dt][r]);
}

// ---------------------------------------------------------------------------
// Combine pass: sum <=4 bf16 chunk partials, normalize, emit bf16.
// ---------------------------------------------------------------------------
__global__ __launch_bounds__(256)
void attn_combine(const u16* __restrict__ po, const float* __restrict__ pl,
                  u16* __restrict__ aob)
{
    const int qt = blockIdx.x;
    const int h  = blockIdx.y;
    const int b  = blockIdx.z;
    const int nc = (qt + 8) >> 3;
    int cum;
    if (qt < 8)       cum = qt;
    else if (qt < 16) cum = 8  + 2 * (qt - 8);
    else if (qt < 24) cum = 24 + 3 * (qt - 16);
    else              cum = 48 + 4 * (qt - 24);
    const int slot0 = (b * H_ + h) * NSLOT + cum;

    const int tid = threadIdx.x;
    const int i   = tid >> 2;
    const int d0  = (tid & 3) * 16;

    float acc[16] = {};
    float lt = 0.0f;
    for (int c = 0; c < nc; ++c) {
        const u16* os = po + (size_t)(slot0 + c) * 4096 + i * 64 + d0;
        s16x8 v0 = *reinterpret_cast<const s16x8*>(os);
        s16x8 v1 = *reinterpret_cast<const s16x8*>(os + 8);
        #pragma unroll
        for (int e = 0; e < 8; ++e) {
            acc[e]     += bf2f((u16)v0[e]);
            acc[8 + e] += bf2f((u16)v1[e]);
        }
        lt += pl[(size_t)(slot0 + c) * 64 + i];
    }
    const float inv = 1.0f / lt;

    u16* dst = aob + (size_t)(b * W_ + qt * 64 + i) * C_ + h * HD + d0;
    s16x8 ov[2];
    #pragma unroll
    for (int e = 0; e < 8; ++e) {
        ov[0][e] = (short)f2bf(acc[e] * inv);
        ov[1][e] = (short)f2bf(acc[8 + e] * inv);
    }
    *reinterpret_cast<s16x8*>(dst)     = ov[0];
    *reinterpret_cast<s16x8*>(dst + 8) = ov[1];
}

// ---------------------------------------------------------------------------
extern "C" void kernel_launch(void* const* d_in, const int* in_sizes, int n_in,
                              void* d_out, int out_size, void* d_ws, size_t ws_size,
                              hipStream_t stream)
{
    const float* x      = (const float*)d_in[0];  // [B,W,C]
    const float* w_attn = (const float*)d_in[1];  // [3C,C]
    const float* w_proj = (const float*)d_in[2];  // [C,C]
    float* out = (float*)d_out;                   // [B,W,C]

    u16* xb   = (u16*)d_ws;                       // [M,  C]
    u16* wab  = xb   + (size_t)M_ * C_;           // [3C, C]
    u16* wpb  = wab  + (size_t)C3 * C_;           // [C,  C]
    u16* qkvb = wpb  + (size_t)C_ * C_;           // [M, 3C]
    u16* aob  = qkvb + (size_t)M_ * C3;           // [M,  C]
    u16* po   = aob  + (size_t)M_ * C_;           // [1920][4096] bf16
    float* pl = (float*)(po + (size_t)B_ * H_ * NSLOT * 4096);  // [1920][64]

    // 0) fp32 -> bf16 conversions (single launch)
    {
        const int total8 = (M_ * C_ + C3 * C_ + C_ * C_) / 8;
        cvt_all<<<(total8 + 255) / 256, 256, 0, stream>>>(
            x, w_attn, w_proj, xb, wab, wpb);
    }

    // 1) QKV projection (bf16 MFMA, 128x128, BK=32, 3-buffer depth-2 prefetch)
    {
        dim3 grid(M_ / 128, C3 / 128);   // 576 blocks
        gemm_nt_mfma<u16><<<grid, 256, 0, stream>>>(xb, wab, qkvb, C3, C_);
    }

    // 2a) KV-split attention partials (1920 blocks, biggest-first)
    {
        dim3 grid(NSLOT, H_, B_);
        attn_partial<<<grid, 256, 0, stream>>>(qkvb, po, pl);
    }
    // 2b) combine + normalize
    {
        dim3 grid(W_ / 64, H_, B_);
        attn_combine<<<grid, 256, 0, stream>>>(po, pl, aob);
    }

    // 3) Output projection: out = aob @ wpb^T (fp32 out)
    {
        dim3 grid(M_ / 128, C_ / 128);   // 192 blocks
        gemm_nt_mfma<float><<<grid, 256, 0, stream>>>(aob, wpb, out, C_, C_);
    }
}